// Round 2
// baseline (2757.594 us; speedup 1.0000x reference)
//
#include <hip/hip_runtime.h>

#define WINDOW 13
#define NTOT   53248          // 13*64*64 voxels per (b,c)
#define WPB    4              // windows per block
#define VT     52             // voxels per block tile
#define NQ     13             // float4 quads per 52-voxel row

// Swizzled tile layout for xsT / vT: element (v, c) lives at
//   base[v*64 + (((c>>2) + v) & 15)*4 + (c&3)]
// -> b128 access of (v, 4cg..4cg+3) is conflict-free across lanes with
//    different v (rows all start at bank 0; swizzle spreads quads).

__global__ __launch_bounds__(256, 3)
void attn_win13_kernel(const float* __restrict__ x,
                       const float* __restrict__ wq, const float* __restrict__ bq,
                       const float* __restrict__ wk, const float* __restrict__ bk,
                       const float* __restrict__ wv, const float* __restrict__ bv,
                       float* __restrict__ out)
{
    // LDS: 5120 + 80 + 3328 + 832 + 3328 + 676 = 13364 floats = 53456 B
    // 3 * 53456 = 160368 <= 163840 -> 3 blocks/CU
    __shared__ float wall[80 * 64];   // rows 0..7 wq, 8..15 wk, 16..79 wv (row-major)
    __shared__ float ball[80];
    __shared__ float xsT[VT * 64];    // swizzled transposed x tile
    __shared__ float qk[16 * VT];     // q rows 0..7, k rows 8..15 (row-major)
    __shared__ float vT[VT * 64];     // swizzled transposed v tile
    __shared__ float att[WPB * 169];  // [w][i][j]

    const int tid = threadIdx.x;
    const int b   = blockIdx.y;
    const int v0  = blockIdx.x * VT;

    // ---- phase 1: stage weights (row-major, b128) + x (transposed+swizzled) ----
    {
        float4* w4 = (float4*)wall;
        if (tid < 128) w4[tid] = ((const float4*)wq)[tid];
        else           w4[tid] = ((const float4*)wk)[tid - 128];
        for (int i = tid; i < 1024; i += 256) w4[256 + i] = ((const float4*)wv)[i];
        if (tid < 8)       ball[tid] = bq[tid];
        else if (tid < 16) ball[tid] = bk[tid - 8];
        else if (tid < 80) ball[tid] = bv[tid - 16];

        for (int i = tid; i < 64 * NQ; i += 256) {
            const int c = i / NQ, q = i % NQ;
            const float4 xv = *(const float4*)(x + (size_t)(b * 64 + c) * NTOT + v0 + q * 4);
            const int cg = c >> 2, cl = c & 3;
            const int va = q * 4;
            xsT[(va + 0) * 64 + ((cg + va + 0) & 15) * 4 + cl] = xv.x;
            xsT[(va + 1) * 64 + ((cg + va + 1) & 15) * 4 + cl] = xv.y;
            xsT[(va + 2) * 64 + ((cg + va + 2) & 15) * 4 + cl] = xv.z;
            xsT[(va + 3) * 64 + ((cg + va + 3) & 15) * 4 + cl] = xv.w;
        }
    }
    __syncthreads();

    // ---- phase 2: qkv = W @ x + bias; 8 rows x 4 voxels per thread ----
    if (tid < 130) {
        const int rb = tid / NQ;      // 0..9 (rb 0,1 -> q,k rows; 2..9 -> v rows)
        const int q  = tid % NQ;
        const int r0 = rb * 8;
        float acc[8][4];
#pragma unroll
        for (int i = 0; i < 8; ++i) {
            const float bias = ball[r0 + i];
#pragma unroll
            for (int k = 0; k < 4; ++k) acc[i][k] = bias;
        }
#pragma unroll
        for (int cb = 0; cb < 16; ++cb) {
            const int g   = (cb + rb) & 15;   // stagger: weight reads hit distinct banks per rb
            const int ch0 = g * 4;
            float4 wr[8];
#pragma unroll
            for (int i = 0; i < 8; ++i)
                wr[i] = *(const float4*)(wall + (r0 + i) * 64 + ch0);
#pragma unroll
            for (int k = 0; k < 4; ++k) {
                const int v = q * 4 + k;
                const float4 xk = *(const float4*)(xsT + v * 64 + ((g + v) & 15) * 4);
#pragma unroll
                for (int i = 0; i < 8; ++i)
                    acc[i][k] += wr[i].x * xk.x + wr[i].y * xk.y
                               + wr[i].z * xk.z + wr[i].w * xk.w;
            }
        }
        if (rb < 2) {
#pragma unroll
            for (int i = 0; i < 8; ++i)
                *(float4*)(qk + (r0 + i) * VT + q * 4) =
                    make_float4(acc[i][0], acc[i][1], acc[i][2], acc[i][3]);
        } else {
            const int cg0 = 2 * rb - 4;       // channel-group of rows r0..r0+3
#pragma unroll
            for (int k = 0; k < 4; ++k) {
                const int v = q * 4 + k;
                *(float4*)(vT + v * 64 + ((cg0     + v) & 15) * 4) =
                    make_float4(acc[0][k], acc[1][k], acc[2][k], acc[3][k]);
                *(float4*)(vT + v * 64 + ((cg0 + 1 + v) & 15) * 4) =
                    make_float4(acc[4][k], acc[5][k], acc[6][k], acc[7][k]);
            }
        }
    }
    __syncthreads();

    // ---- phase 3a: scores[w][i][j] = sum_o q[o][w,i] * k[o][w,j] ----
    for (int f = tid; f < WPB * 169; f += 256) {
        const int w = f / 169, rem = f % 169;
        const int i = rem / 13, j = rem % 13;
        float s = 0.f;
#pragma unroll
        for (int o = 0; o < 8; ++o)
            s += qk[o * VT + w * 13 + i] * qk[(8 + o) * VT + w * 13 + j];
        att[f] = s;
    }
    __syncthreads();

    // ---- phase 3b: softmax over j ----
    if (tid < WPB * WINDOW) {
        float* row = att + tid * 13;
        float m = row[0];
#pragma unroll
        for (int j = 1; j < 13; ++j) m = fmaxf(m, row[j]);
        float e[13]; float sum = 0.f;
#pragma unroll
        for (int j = 0; j < 13; ++j) { e[j] = __expf(row[j] - m); sum += e[j]; }
        const float inv = 1.f / sum;
#pragma unroll
        for (int j = 0; j < 13; ++j) row[j] = e[j] * inv;
    }
    __syncthreads();

    // ---- phase 4: out[4cg+t][vx] = sum_j vT[w13+j][c] * att[w][i][j] ----
    for (int f = tid; f < 16 * VT; f += 256) {
        const int cg = f / VT;        // channel group 0..15
        const int vx = f % VT;        // voxel in tile
        const int w  = vx / 13, i = vx % 13;
        const float* arow = att + w * 169 + i * 13;
        float4 a4 = make_float4(0.f, 0.f, 0.f, 0.f);
#pragma unroll
        for (int j = 0; j < 13; ++j) {
            const int vv = w * 13 + j;
            const float4 vvv = *(const float4*)(vT + vv * 64 + ((cg + vv) & 15) * 4);
            const float a = arow[j];
            a4.x += a * vvv.x; a4.y += a * vvv.y; a4.z += a * vvv.z; a4.w += a * vvv.w;
        }
        float* op = out + (size_t)(b * 64 + cg * 4) * NTOT + v0 + vx;
        op[0]        = a4.x;
        op[NTOT]     = a4.y;
        op[2*NTOT]   = a4.z;
        op[3L*NTOT]  = a4.w;
    }
}

extern "C" void kernel_launch(void* const* d_in, const int* in_sizes, int n_in,
                              void* d_out, int out_size, void* d_ws, size_t ws_size,
                              hipStream_t stream) {
    const float* x  = (const float*)d_in[0];
    const float* wq = (const float*)d_in[1];
    const float* bq = (const float*)d_in[2];
    const float* wk = (const float*)d_in[3];
    const float* bk = (const float*)d_in[4];
    const float* wv = (const float*)d_in[5];
    const float* bv = (const float*)d_in[6];
    float* out = (float*)d_out;

    dim3 grid(NTOT / VT, 8);   // 1024 tiles x 8 batches
    dim3 block(256);
    attn_win13_kernel<<<grid, block, 0, stream>>>(x, wq, bq, wk, bk, wv, bv, out);
}

// Round 3
// 259.041 us; speedup vs baseline: 10.6454x; 10.6454x over previous
//
#include <hip/hip_runtime.h>

#define WINDOW 13
#define NTOT   53248      // 13*64*64 voxels per (b,c)
#define WPB    8          // windows per block
#define VT     104        // real voxels per block (8 windows)
#define VS     112        // staged voxels (7 MFMA col-tiles of 16)
#define WS     72         // bf16 row stride (pad 64->72: bank-quad step 1, conflict-free b128)
#define QKS    112        // qk fp32 row stride
#define VFS    68         // v fp32 row stride (pad 64->68)

typedef float floatx4 __attribute__((ext_vector_type(4)));
typedef short shortx8 __attribute__((ext_vector_type(8)));

__device__ __forceinline__ unsigned short f2bf(float f) {
    union { float f; unsigned int u; } v; v.f = f;
    unsigned int u = v.u;
    unsigned int r = (u + 0x7fffu + ((u >> 16) & 1u)) >> 16;   // RNE
    return (unsigned short)r;
}

__global__ __launch_bounds__(256, 4)
void attn_win13_kernel(const float* __restrict__ x,
                       const float* __restrict__ wq, const float* __restrict__ bq,
                       const float* __restrict__ wk, const float* __restrict__ bk,
                       const float* __restrict__ wv, const float* __restrict__ bv,
                       float* __restrict__ out)
{
    // LDS: 16128 + 11520 + 320 + 30464 + 7168 + 5408 = 71008 B -> 2 blocks/CU
    __shared__ unsigned short xT[VS * WS];   // bf16 x, transposed [vox][ch], padded
    __shared__ unsigned short wbf[80 * WS];  // bf16 weights, rows 0..7 q, 8..15 k, 16..79 v
    __shared__ float ball[80];
    __shared__ float vf[VS * VFS];           // fp32 v, [vox][ch], padded
    __shared__ float qk[16 * QKS];           // fp32 q rows 0..7, k rows 8..15
    __shared__ float att[WPB * 169];         // [w][i][j]

    const int tid = threadIdx.x;
    const int b   = blockIdx.y;
    const int v0  = blockIdx.x * VT;
    const size_t total = (size_t)512 * NTOT;   // 8*64 rows of x

    // ---- P1a: weights (fp32 global -> bf16 LDS, padded rows) + biases ----
    for (int f = tid; f < 1280; f += 256) {          // 80 rows * 16 quads
        const int r = f >> 4, c = (f & 15) * 4;
        const float* src = (r < 8)  ? (wq + r * 64 + c)
                         : (r < 16) ? (wk + (r - 8) * 64 + c)
                                    : (wv + (r - 16) * 64 + c);
        const float4 w4 = *(const float4*)src;
        *(unsigned int*)(&wbf[r * WS + c])     = (unsigned int)f2bf(w4.x) | ((unsigned int)f2bf(w4.y) << 16);
        *(unsigned int*)(&wbf[r * WS + c + 2]) = (unsigned int)f2bf(w4.z) | ((unsigned int)f2bf(w4.w) << 16);
    }
    if (tid < 80)
        ball[tid] = (tid < 8) ? bq[tid] : (tid < 16) ? bk[tid - 8] : bv[tid - 16];

    // ---- P1b: x (fp32 global -> bf16 transposed LDS). Stage 112 voxels; the
    // 8 beyond VT are MFMA garbage columns, clamped at the buffer tail. ----
    for (int f = tid; f < 896; f += 256) {           // 32 ch-pairs * 28 vox-quads
        const int cp = f / 28, vq = f % 28;
        const int c = cp * 2, vx = vq * 4;
        size_t i0 = (size_t)(b * 64 + c) * NTOT + v0 + vx;
        size_t i1 = i0 + NTOT;
        if (i0 > total - 4) i0 = total - 4;
        if (i1 > total - 4) i1 = total - 4;
        const float4 x0 = *(const float4*)(x + i0);  // channel c,   vox vx..vx+3
        const float4 x1 = *(const float4*)(x + i1);  // channel c+1, vox vx..vx+3
        *(unsigned int*)(&xT[(vx + 0) * WS + c]) = (unsigned int)f2bf(x0.x) | ((unsigned int)f2bf(x1.x) << 16);
        *(unsigned int*)(&xT[(vx + 1) * WS + c]) = (unsigned int)f2bf(x0.y) | ((unsigned int)f2bf(x1.y) << 16);
        *(unsigned int*)(&xT[(vx + 2) * WS + c]) = (unsigned int)f2bf(x0.z) | ((unsigned int)f2bf(x1.z) << 16);
        *(unsigned int*)(&xT[(vx + 3) * WS + c]) = (unsigned int)f2bf(x0.w) | ((unsigned int)f2bf(x1.w) << 16);
    }
    __syncthreads();

    // ---- P2: projection GEMM via MFMA. 5 m-tiles x 7 n-tiles, K=64 (2 mfma).
    // A-frag: m=lane&15, k=(lane>>4)*8+j ; B-frag: n=lane&15, same k-chunks;
    // D: row=(lane>>4)*4+reg, col=lane&15  [m89/m91-verified]. ----
    {
        const int wid  = tid >> 6;
        const int lane = tid & 63;
        const int col  = lane & 15;
        const int g    = lane >> 4;          // k-chunk / row-quad
        for (int t = wid; t < 35; t += 4) {
            const int mt = t / 7, nt = t % 7;
            const shortx8 a0 = *(const shortx8*)(&wbf[(mt * 16 + col) * WS + g * 8]);
            const shortx8 b0 = *(const shortx8*)(&xT [(nt * 16 + col) * WS + g * 8]);
            const shortx8 a1 = *(const shortx8*)(&wbf[(mt * 16 + col) * WS + 32 + g * 8]);
            const shortx8 b1 = *(const shortx8*)(&xT [(nt * 16 + col) * WS + 32 + g * 8]);
            floatx4 acc = {0.f, 0.f, 0.f, 0.f};
            acc = __builtin_amdgcn_mfma_f32_16x16x32_bf16(a0, b0, acc, 0, 0, 0);
            acc = __builtin_amdgcn_mfma_f32_16x16x32_bf16(a1, b1, acc, 0, 0, 0);
            const int row0 = mt * 16 + g * 4;
            const int vox  = nt * 16 + col;
            if (mt == 0) {                    // q/k rows -> qk (fp32, row-major)
                qk[(row0 + 0) * QKS + vox] = acc[0] + ball[row0 + 0];
                qk[(row0 + 1) * QKS + vox] = acc[1] + ball[row0 + 1];
                qk[(row0 + 2) * QKS + vox] = acc[2] + ball[row0 + 2];
                qk[(row0 + 3) * QKS + vox] = acc[3] + ball[row0 + 3];
            } else {                          // v rows: 4 consecutive channels -> one b128
                const int c0 = row0 - 16;
                float4 st = make_float4(acc[0] + ball[row0 + 0], acc[1] + ball[row0 + 1],
                                        acc[2] + ball[row0 + 2], acc[3] + ball[row0 + 3]);
                *(float4*)(&vf[vox * VFS + c0]) = st;
            }
        }
    }
    __syncthreads();

    // ---- P3a: scores[w][i][j] = sum_o q[o][w13+i] * k[o][w13+j] ----
    for (int f = tid; f < WPB * 169; f += 256) {
        const int w = f / 169, rem = f % 169;
        const int i = rem / 13, j = rem % 13;
        const float* qp = &qk[w * 13 + i];
        const float* kp = &qk[w * 13 + j];
        float s = 0.f;
#pragma unroll
        for (int o = 0; o < 8; ++o)
            s += qp[o * QKS] * kp[(8 + o) * QKS];
        att[f] = s;
    }
    __syncthreads();

    // ---- P3b: softmax over j (one thread per (w,i) row) ----
    if (tid < WPB * WINDOW) {
        float* row = att + tid * 13;
        float m = row[0];
#pragma unroll
        for (int j = 1; j < 13; ++j) m = fmaxf(m, row[j]);
        float s0 = __expf(row[0] - m), s1 = __expf(row[1] - m), s2 = __expf(row[2] - m);
        float s3 = __expf(row[3] - m), s4 = __expf(row[4] - m), s5 = __expf(row[5] - m);
        float s6 = __expf(row[6] - m), s7 = __expf(row[7] - m), s8 = __expf(row[8] - m);
        float s9 = __expf(row[9] - m), sa = __expf(row[10] - m), sb = __expf(row[11] - m);
        float sc = __expf(row[12] - m);
        const float inv = 1.f / (s0+s1+s2+s3+s4+s5+s6+s7+s8+s9+sa+sb+sc);
        row[0]=s0*inv; row[1]=s1*inv; row[2]=s2*inv; row[3]=s3*inv; row[4]=s4*inv;
        row[5]=s5*inv; row[6]=s6*inv; row[7]=s7*inv; row[8]=s8*inv; row[9]=s9*inv;
        row[10]=sa*inv; row[11]=sb*inv; row[12]=sc*inv;
    }
    __syncthreads();

    // ---- P4: out[4cg+r][vx] = sum_j vf[w13+j][4cg+r] * att[w][i][j].
    // vx-fast mapping -> all 4 global store instrs are voxel-contiguous. ----
    for (int f = tid; f < 16 * VT; f += 256) {
        const int cg = f / VT, vx = f % VT;
        const int w = vx / 13, i = vx % 13;
        const float* arow  = att + w * 169 + i * 13;
        const float* vbase = &vf[(w * 13) * VFS + cg * 4];
        float4 o4 = make_float4(0.f, 0.f, 0.f, 0.f);
#pragma unroll
        for (int j = 0; j < 13; ++j) {
            const float a = arow[j];
            const float4 vv = *(const float4*)(vbase + j * VFS);
            o4.x += a * vv.x; o4.y += a * vv.y; o4.z += a * vv.z; o4.w += a * vv.w;
        }
        float* op = out + (size_t)(b * 64 + cg * 4) * NTOT + v0 + vx;
        op[0]                 = o4.x;
        op[(size_t)NTOT]      = o4.y;
        op[(size_t)2 * NTOT]  = o4.z;
        op[(size_t)3 * NTOT]  = o4.w;
    }
}

extern "C" void kernel_launch(void* const* d_in, const int* in_sizes, int n_in,
                              void* d_out, int out_size, void* d_ws, size_t ws_size,
                              hipStream_t stream) {
    const float* x  = (const float*)d_in[0];
    const float* wq = (const float*)d_in[1];
    const float* bq = (const float*)d_in[2];
    const float* wk = (const float*)d_in[3];
    const float* bk = (const float*)d_in[4];
    const float* wv = (const float*)d_in[5];
    const float* bv = (const float*)d_in[6];
    float* out = (float*)d_out;

    dim3 grid(NTOT / VT, 8);   // 512 tiles x 8 batches = 4096 blocks
    dim3 block(256);
    attn_win13_kernel<<<grid, block, 0, stream>>>(x, wq, bq, wk, bk, wv, bv, out);
}